// Round 7
// baseline (183.153 us; speedup 1.0000x reference)
//
#include <hip/hip_runtime.h>
#include <math.h>

#define NFFT   1024
#define HOPS   256
#define WINL   1024
#define PADL   384
#define BATCH  16
#define NFRAMES 2048
#define SPEC_K 513
#define SPEC_T 2048
#define OUT_PER_B  524288   // (NFRAMES-1)*HOP + WIN - 2*PAD
#define FULL_PER_B 525056   // (NFRAMES-1)*HOP + WIN

#define COLS 16      // frames per block
#define STRIDEF 13   // finalize stride in frames (blocks overlap by 3 frames)
#define JBLK 158     // blocks per batch: (157*13+16)*256 >= 525056
#define NTHREADS 512
#define FSTRIDE 575  // C2/row. ODD -> row stride 1150 dwords ≡ 30 mod 32: 16 frame rows
                     // hit 16 distinct bank-pairs -> phase-1 col-writes conflict-free.
                     // Max IDX(511) = 574 < 575. LDS 16*575*8+4096 = 77.7KB -> 2 blocks/CU.

struct C2 { float x, y; };

__device__ __forceinline__ C2 cadd(C2 a, C2 b){ return {a.x+b.x, a.y+b.y}; }
__device__ __forceinline__ C2 csub(C2 a, C2 b){ return {a.x-b.x, a.y-b.y}; }
__device__ __forceinline__ C2 cmul(C2 a, C2 b){ return {a.x*b.x - a.y*b.y, a.x*b.y + a.y*b.x}; }
__device__ __forceinline__ C2 muli(C2 a){ return {-a.y, a.x}; }   // multiply by +i

// Zero-cost compiler fence: pins LDS access order across FFT stages.
// HW already executes same-wave DS ops in program order (in-order DS is what
// makes counted lgkmcnt waits valid); each FFT column is owned by ONE wave,
// so no cross-wave barrier is needed inside phase 2.
#define CFENCE() asm volatile("" ::: "memory")

// 8-point inverse DFT (no scale): y[j] = sum_i x[i] e^{+2pi i * i*j/8}
__device__ __forceinline__ void idft8(C2* v) {
    C2 e0=v[0], e1=v[2], e2=v[4], e3=v[6];
    C2 o0=v[1], o1=v[3], o2=v[5], o3=v[7];
    C2 a0=cadd(e0,e2), a1=csub(e0,e2), a2=cadd(e1,e3), a3=csub(e1,e3);
    C2 E0=cadd(a0,a2), E1=cadd(a1,muli(a3)), E2=csub(a0,a2), E3=csub(a1,muli(a3));
    C2 b0=cadd(o0,o2), b1=csub(o0,o2), b2=cadd(o1,o3), b3=csub(o1,o3);
    C2 O0=cadd(b0,b2), O1=cadd(b1,muli(b3)), O2=csub(b0,b2), O3=csub(b1,muli(b3));
    const float s = 0.7071067811865476f;
    C2 t1 = {  s*(O1.x - O1.y), s*(O1.x + O1.y) };
    C2 t2 = muli(O2);
    C2 t3 = { -s*(O3.x + O3.y), s*(O3.x - O3.y) };
    v[0]=cadd(E0,O0); v[4]=csub(E0,O0);
    v[1]=cadd(E1,t1); v[5]=csub(E1,t1);
    v[2]=cadd(E2,t2); v[6]=csub(E2,t2);
    v[3]=cadd(E3,t3); v[7]=csub(E3,t3);
}

// intra-frame LDS padding: +1 C2 per 8 C2 (conflict-free for all FFT stages + phase-1)
__device__ __forceinline__ int IDX(int x){ return x + (x>>3); }

__global__ __launch_bounds__(NTHREADS, 4)
void istft_kernel(const float* __restrict__ sr, const float* __restrict__ si,
                  const float* __restrict__ win, float* __restrict__ out)
{
    __shared__ C2    fbuf[COLS][FSTRIDE];  // packed spectrum -> FFT workspace -> windowed frame
    __shared__ float swin[WINL];

    // XCD-aware swizzle: consecutive logical j land on the same XCD (L2 reuse of overlap)
    int h  = blockIdx.x;
    int L  = (h & 7) * (BATCH*JBLK/8) + (h >> 3);
    int b  = L / JBLK;
    int j  = L - b*JBLK;
    int t0 = j * STRIDEF;
    int tid = threadIdx.x;
    int lane = tid & 63, wave = tid >> 6;   // 8 waves

    for (int i = tid; i < WINL; i += NTHREADS) swin[i] = win[i];

    // ---- per-lane register twiddles via complex-multiply recursion (2 sincos total) ----
    int m02 = lane >> 3, a2 = lane & 7;
    int up  = m02 + 8*a2;            // stage-3 u index
    float c2r[8], c2i[8], c3r[8], c3i[8];
    {
        float s2, co2; __sincosf((float)m02 * 0.09817477042468103f,  &s2, &co2);  // 2pi/64
        float s3, co3; __sincosf((float)up  * 0.012271846303085129f, &s3, &co3);  // 2pi/512
        c2r[1] = co2; c2i[1] = s2;
        c3r[1] = co3; c3i[1] = s3;
        #pragma unroll
        for (int q = 2; q < 8; ++q) {
            float pr = c2r[q-1], pi = c2i[q-1];
            c2r[q] = pr*co2 - pi*s2;
            c2i[q] = pi*co2 + pr*s2;
            float qr = c3r[q-1], qi = c3i[q-1];
            c3r[q] = qr*co3 - qi*s3;
            c3i[q] = qi*co3 + qr*s3;
        }
    }

    // ---- phase 1: global load + pack W[k] = (E[k] + i*O[k])/512 ----
    // Fully unrolled 8-deep: loads issued up front (pipelined), twiddle by recursion.
    // Thread layout: tt = tid&15 (frame), kp = (tid>>4) + 32*i  -> 64B coalesced segments.
    const float* srb = sr + (size_t)b * SPEC_K * SPEC_T;
    const float* sib = si + (size_t)b * SPEC_K * SPEC_T;
    const float inv512 = 1.0f/512.0f;
    {
        const int tt  = tid & 15;
        const int kp0 = tid >> 4;        // 0..31
        const int t   = t0 + tt;
        if (t < NFRAMES) {
            const float* pr = srb + t;
            const float* pq = sib + t;
            float Arr[8], Aii[8], Brr[8], Bii[8];
            #pragma unroll
            for (int i = 0; i < 8; ++i) {
                const int kp   = kp0 + 32*i;
                const int krev = 512 - kp;
                Arr[i] = pr[(size_t)kp  * SPEC_T];
                Aii[i] = pq[(size_t)kp  * SPEC_T];
                Brr[i] = pr[(size_t)krev* SPEC_T];
                Bii[i] = pq[(size_t)krev* SPEC_T];
            }
            float ss, cc;
            __sincosf((float)kp0 * 0.006135923151542565f, &ss, &cc);   // 2pi/1024
            const float stc = 0.98078528040323044f;   // cos(2pi*32/1024)
            const float sts = 0.19509032201612827f;   // sin(2pi*32/1024)
            #pragma unroll
            for (int i = 0; i < 8; ++i) {
                const int kp = kp0 + 32*i;
                float Ar = Arr[i], Ai = Aii[i], Br = Brr[i], Bi = Bii[i];
                if (i == 0 && kp0 == 0) { Ai = 0.f; Bi = 0.f; }  // bin 0/512 real
                float Er = 0.5f*(Ar+Br), Ei = 0.5f*(Ai-Bi);
                float Dr = 0.5f*(Ar-Br), Di = 0.5f*(Ai+Bi);
                float Or = cc*Dr - ss*Di, Oi = cc*Di + ss*Dr;
                fbuf[tt][IDX(kp)] = { (Er - Oi)*inv512, (Ei + Or)*inv512 };
                if (i > 0 || kp0 > 0)
                    fbuf[tt][IDX(512-kp)] = { (Er + Oi)*inv512, (Or - Ei)*inv512 };
                float nc = cc*stc - ss*sts;
                float ns = ss*stc + cc*sts;
                cc = nc; ss = ns;
            }
            if (kp0 == 0) {   // kp = 256 tail (threads 0..15, tt == tid)
                float Ar = pr[(size_t)256 * SPEC_T];
                float Ai = pq[(size_t)256 * SPEC_T];
                fbuf[tt][IDX(256)] = { Ar*inv512, -Ai*inv512 };
            }
        }
    }
    __syncthreads();   // cross-wave: phase-1 writes all columns -> phase-2 reads

    // ---- phase 2: per-wave 512-pt inverse FFT (3 x radix-8, in-place)
    //      8 waves x 2 columns each (cols wave, wave+8). Each column is owned by
    //      exactly ONE wave, so all stage hand-offs are intra-wave: HW executes
    //      same-wave DS ops in order, compiler order pinned by CFENCE -> NO
    //      barriers needed inside this phase. Waves stream independently,
    //      staggering LDS bursts against VALU bursts across the CU. ----
    {
        const int colA = wave, colB = wave + 8;
        const bool actA = (t0 + colA) < NFRAMES;
        const bool actB = (t0 + colB) < NFRAMES;
        C2* bufA = fbuf[colA];
        C2* bufB = fbuf[colB];
        C2 va[8], vb[8];

        // stage 1: [lane + 64c] -> [lane + 64m0]  (lane-local address set)
        if (actA) {
            #pragma unroll
            for (int c = 0; c < 8; ++c) va[c] = bufA[IDX(lane + 64*c)];
            idft8(va);
            #pragma unroll
            for (int m0 = 0; m0 < 8; ++m0) bufA[IDX(lane + 64*m0)] = va[m0];
        }
        if (actB) {
            #pragma unroll
            for (int c = 0; c < 8; ++c) vb[c] = bufB[IDX(lane + 64*c)];
            idft8(vb);
            #pragma unroll
            for (int m0 = 0; m0 < 8; ++m0) bufB[IDX(lane + 64*m0)] = vb[m0];
        }
        CFENCE();   // intra-wave RAW: stage-1 writes -> stage-2 reads (HW in-order DS)

        // stage 2: [a + 8b + 64m0] --tw--> [a + 8m1 + 64m0]  (lane-local address set)
        const int base2 = a2 + 64*m02;
        if (actA) {
            #pragma unroll
            for (int bb = 0; bb < 8; ++bb) va[bb] = bufA[IDX(base2 + 8*bb)];
            #pragma unroll
            for (int bb = 1; bb < 8; ++bb) va[bb] = cmul(va[bb], {c2r[bb], c2i[bb]});
            idft8(va);
            #pragma unroll
            for (int m1 = 0; m1 < 8; ++m1) bufA[IDX(base2 + 8*m1)] = va[m1];
        }
        if (actB) {
            #pragma unroll
            for (int bb = 0; bb < 8; ++bb) vb[bb] = bufB[IDX(base2 + 8*bb)];
            #pragma unroll
            for (int bb = 1; bb < 8; ++bb) vb[bb] = cmul(vb[bb], {c2r[bb], c2i[bb]});
            idft8(vb);
            #pragma unroll
            for (int m1 = 0; m1 < 8; ++m1) bufB[IDX(base2 + 8*m1)] = vb[m1];
        }
        CFENCE();   // intra-wave RAW: stage-2 writes -> stage-3 reads

        // stage 3: contiguous read [8*lane + a], tw, idft8 — both cols (no writes yet)
        if (actA) {
            #pragma unroll
            for (int aa = 0; aa < 8; ++aa) va[aa] = bufA[IDX(8*lane + aa)];
            #pragma unroll
            for (int aa = 1; aa < 8; ++aa) va[aa] = cmul(va[aa], {c3r[aa], c3i[aa]});
            idft8(va);
        }
        if (actB) {
            #pragma unroll
            for (int aa = 0; aa < 8; ++aa) vb[aa] = bufB[IDX(8*lane + aa)];
            #pragma unroll
            for (int aa = 1; aa < 8; ++aa) vb[aa] = cmul(vb[aa], {c3r[aa], c3i[aa]});
            idft8(vb);
        }
        // window coefficients: lane-dependent only — load once, use for both cols
        float2 wv[8];
        #pragma unroll
        for (int m2 = 0; m2 < 8; ++m2) wv[m2] = *(const float2*)&swin[2*(up + 64*m2)];
        CFENCE();   // intra-wave WAR: stage-3 reads precede linear overwrite (in-order DS)

        // unpack z[m] -> x[2m], x[2m+1]; apply window; write frame as floats (contiguous)
        if (actA) {
            float* f = (float*)bufA;
            #pragma unroll
            for (int m2 = 0; m2 < 8; ++m2) {
                int n = 2*(up + 64*m2);
                float2 val = { va[m2].x * wv[m2].x, va[m2].y * wv[m2].y };
                *(float2*)&f[n] = val;
            }
        }
        if (actB) {
            float* f = (float*)bufB;
            #pragma unroll
            for (int m2 = 0; m2 < 8; ++m2) {
                int n = 2*(up + 64*m2);
                float2 val = { vb[m2].x * wv[m2].x, vb[m2].y * wv[m2].y };
                *(float2*)&f[n] = val;
            }
        }
    }
    __syncthreads();   // cross-wave: all columns final -> phase-3 reads any column

    // ---- phase 3: finalize exclusive span: sum <=4 windowed frames + env division ----
    // Fast path: p mod 256 is per-thread invariant -> envelope (4 taps + 1 rcp) hoisted.
    int p_start = (j == 0) ? 0 : (t0 + 3) * HOPS;
    int p_end   = (t0 + COLS) * HOPS;
    if (p_end > FULL_PER_B) p_end = FULL_PER_B;
    float* outb = out + (size_t)b * OUT_PER_B;
    const float* fb = (const float*)fbuf;    // row stride = 2*FSTRIDE = 1150 floats
    const int p0 = p_start + tid;
    const int q  = p0 & 255;                 // stride NTHREADS=512 preserves q
    float w3 = swin[q], w2 = swin[q+256], w1 = swin[q+512], w0 = swin[q+768];
    float inv4 = 1.0f / fmaxf(w0*w0 + w1*w1 + w2*w2 + w3*w3, 1e-11f);
    for (int p = p0; p < p_end; p += NTHREADS) {
        if (p >= 768 && p < 524288) {
            // interior: exactly 4 frames, env per-thread invariant
            int d = ((p >> 8) - 3) - t0;         // 0..COLS-4
            const float* r = fb + (size_t)d * (2*FSTRIDE);
            float sum = r[q+768] + r[(2*FSTRIDE) + q+512] + r[(4*FSTRIDE) + q+256]
                      + r[(6*FSTRIDE) + q];
            outb[p - PADL] = sum * inv4;
        } else {
            int o = p - PADL;
            if (o < 0 || o >= OUT_PER_B) continue;
            int thi = p >> 8;          if (thi > NFRAMES-1) thi = NFRAMES-1;
            int tlo = (p - 768) >> 8;  if (tlo < 0) tlo = 0;
            float sum = 0.f, env = 0.f;
            for (int t = tlo; t <= thi; ++t) {
                int n = p - (t << 8);
                float w = swin[n];
                sum += fb[(size_t)(t - t0) * (2*FSTRIDE) + n];
                env += w * w;
            }
            outb[o] = sum / fmaxf(env, 1e-11f);
        }
    }
}

extern "C" void kernel_launch(void* const* d_in, const int* in_sizes, int n_in,
                              void* d_out, int out_size, void* d_ws, size_t ws_size,
                              hipStream_t stream) {
    const float* sr  = (const float*)d_in[0];
    const float* si  = (const float*)d_in[1];
    const float* win = (const float*)d_in[2];
    float* out = (float*)d_out;
    istft_kernel<<<dim3(BATCH*JBLK), dim3(NTHREADS), 0, stream>>>(sr, si, win, out);
}

// Round 8
// 175.237 us; speedup vs baseline: 1.0452x; 1.0452x over previous
//
#include <hip/hip_runtime.h>
#include <math.h>

#define NFFT   1024
#define HOPS   256
#define WINL   1024
#define PADL   384
#define BATCH  16
#define NFRAMES 2048
#define SPEC_K 513
#define SPEC_T 2048
#define OUT_PER_B  524288   // (NFRAMES-1)*HOP + WIN - 2*PAD
#define FULL_PER_B 525056   // (NFRAMES-1)*HOP + WIN

#define COLS 16      // frames per block
#define STRIDEF 13   // finalize stride in frames (blocks overlap by 3 frames)
#define JBLK 158     // blocks per batch: (157*13+16)*256 >= 525056
#define NTHREADS 1024  // 16 waves: ONE FFT column per wave; 2 blocks/CU = 32 waves/CU (100%)
#define FSTRIDE 575  // C2/row. ODD -> row stride 1150 dwords ≡ 30 mod 32: 16 frame rows
                     // hit 16 distinct bank-pairs -> phase-1 col-writes conflict-free.
                     // Max IDX(511) = 574 < 575. LDS 16*575*8+4096 = 77.7KB -> 2 blocks/CU.

struct C2 { float x, y; };

__device__ __forceinline__ C2 cadd(C2 a, C2 b){ return {a.x+b.x, a.y+b.y}; }
__device__ __forceinline__ C2 csub(C2 a, C2 b){ return {a.x-b.x, a.y-b.y}; }
__device__ __forceinline__ C2 cmul(C2 a, C2 b){ return {a.x*b.x - a.y*b.y, a.x*b.y + a.y*b.x}; }
__device__ __forceinline__ C2 muli(C2 a){ return {-a.y, a.x}; }   // multiply by +i

// Zero-cost compiler fence: pins LDS access order across FFT stages.
// HW already executes same-wave DS ops in program order; each FFT column is
// owned by ONE wave, so no cross-wave barrier is needed inside phase 2.
// (Verified R7: passes replay-determinism check.)
#define CFENCE() asm volatile("" ::: "memory")

// 8-point inverse DFT (no scale): y[j] = sum_i x[i] e^{+2pi i * i*j/8}
__device__ __forceinline__ void idft8(C2* v) {
    C2 e0=v[0], e1=v[2], e2=v[4], e3=v[6];
    C2 o0=v[1], o1=v[3], o2=v[5], o3=v[7];
    C2 a0=cadd(e0,e2), a1=csub(e0,e2), a2=cadd(e1,e3), a3=csub(e1,e3);
    C2 E0=cadd(a0,a2), E1=cadd(a1,muli(a3)), E2=csub(a0,a2), E3=csub(a1,muli(a3));
    C2 b0=cadd(o0,o2), b1=csub(o0,o2), b2=cadd(o1,o3), b3=csub(o1,o3);
    C2 O0=cadd(b0,b2), O1=cadd(b1,muli(b3)), O2=csub(b0,b2), O3=csub(b1,muli(b3));
    const float s = 0.7071067811865476f;
    C2 t1 = {  s*(O1.x - O1.y), s*(O1.x + O1.y) };
    C2 t2 = muli(O2);
    C2 t3 = { -s*(O3.x + O3.y), s*(O3.x - O3.y) };
    v[0]=cadd(E0,O0); v[4]=csub(E0,O0);
    v[1]=cadd(E1,t1); v[5]=csub(E1,t1);
    v[2]=cadd(E2,t2); v[6]=csub(E2,t2);
    v[3]=cadd(E3,t3); v[7]=csub(E3,t3);
}

// intra-frame LDS padding: +1 C2 per 8 C2 (conflict-free for all FFT stages + phase-1)
__device__ __forceinline__ int IDX(int x){ return x + (x>>3); }

__global__ __launch_bounds__(NTHREADS, 8)
void istft_kernel(const float* __restrict__ sr, const float* __restrict__ si,
                  const float* __restrict__ win, float* __restrict__ out)
{
    __shared__ C2    fbuf[COLS][FSTRIDE];  // packed spectrum -> FFT workspace -> windowed frame
    __shared__ float swin[WINL];

    // XCD-aware swizzle: consecutive logical j land on the same XCD (L2 reuse of overlap)
    int h  = blockIdx.x;
    int L  = (h & 7) * (BATCH*JBLK/8) + (h >> 3);
    int b  = L / JBLK;
    int j  = L - b*JBLK;
    int t0 = j * STRIDEF;
    int tid = threadIdx.x;
    int lane = tid & 63, wave = tid >> 6;   // 16 waves

    for (int i = tid; i < WINL; i += NTHREADS) swin[i] = win[i];

    // ---- per-lane register twiddles via complex-multiply recursion (2 sincos total) ----
    int m02 = lane >> 3, a2 = lane & 7;
    int up  = m02 + 8*a2;            // stage-3 u index
    float c2r[8], c2i[8], c3r[8], c3i[8];
    {
        float s2, co2; __sincosf((float)m02 * 0.09817477042468103f,  &s2, &co2);  // 2pi/64
        float s3, co3; __sincosf((float)up  * 0.012271846303085129f, &s3, &co3);  // 2pi/512
        c2r[1] = co2; c2i[1] = s2;
        c3r[1] = co3; c3i[1] = s3;
        #pragma unroll
        for (int q = 2; q < 8; ++q) {
            float pr = c2r[q-1], pi = c2i[q-1];
            c2r[q] = pr*co2 - pi*s2;
            c2i[q] = pi*co2 + pr*s2;
            float qr = c3r[q-1], qi = c3i[q-1];
            c3r[q] = qr*co3 - qi*s3;
            c3i[q] = qi*co3 + qr*s3;
        }
    }

    // ---- phase 1: global load + pack W[k] = (E[k] + i*O[k])/512 ----
    // 4-deep unroll: loads issued up front (pipelined), twiddle by recursion.
    // Thread layout: tt = tid&15 (frame), kp = (tid>>4) + 64*i  -> 64B coalesced segments.
    const float* srb = sr + (size_t)b * SPEC_K * SPEC_T;
    const float* sib = si + (size_t)b * SPEC_K * SPEC_T;
    const float inv512 = 1.0f/512.0f;
    {
        const int tt  = tid & 15;
        const int kp0 = tid >> 4;        // 0..63
        const int t   = t0 + tt;
        if (t < NFRAMES) {
            const float* pr = srb + t;
            const float* pq = sib + t;
            float Arr[4], Aii[4], Brr[4], Bii[4];
            #pragma unroll
            for (int i = 0; i < 4; ++i) {
                const int kp   = kp0 + 64*i;
                const int krev = 512 - kp;
                Arr[i] = pr[(size_t)kp  * SPEC_T];
                Aii[i] = pq[(size_t)kp  * SPEC_T];
                Brr[i] = pr[(size_t)krev* SPEC_T];
                Bii[i] = pq[(size_t)krev* SPEC_T];
            }
            float ss, cc;
            __sincosf((float)kp0 * 0.006135923151542565f, &ss, &cc);   // 2pi/1024
            const float stc = 0.92387953251128674f;   // cos(2pi*64/1024) = cos(pi/8)
            const float sts = 0.38268343236508978f;   // sin(pi/8)
            #pragma unroll
            for (int i = 0; i < 4; ++i) {
                const int kp = kp0 + 64*i;
                float Ar = Arr[i], Ai = Aii[i], Br = Brr[i], Bi = Bii[i];
                if (i == 0 && kp0 == 0) { Ai = 0.f; Bi = 0.f; }  // bin 0/512 real
                float Er = 0.5f*(Ar+Br), Ei = 0.5f*(Ai-Bi);
                float Dr = 0.5f*(Ar-Br), Di = 0.5f*(Ai+Bi);
                float Or = cc*Dr - ss*Di, Oi = cc*Di + ss*Dr;
                fbuf[tt][IDX(kp)] = { (Er - Oi)*inv512, (Ei + Or)*inv512 };
                if (i > 0 || kp0 > 0)
                    fbuf[tt][IDX(512-kp)] = { (Er + Oi)*inv512, (Or - Ei)*inv512 };
                float nc = cc*stc - ss*sts;
                float ns = ss*stc + cc*sts;
                cc = nc; ss = ns;
            }
            if (kp0 == 0) {   // kp = 256 tail (threads 0..15, tt == tid)
                float Ar = pr[(size_t)256 * SPEC_T];
                float Ai = pq[(size_t)256 * SPEC_T];
                fbuf[tt][IDX(256)] = { Ar*inv512, -Ai*inv512 };
            }
        }
    }
    __syncthreads();   // cross-wave: phase-1 writes all columns -> phase-2 reads

    // ---- phase 2: per-wave 512-pt inverse FFT (3 x radix-8, in-place)
    //      16 waves x 1 column each. Each column owned by ONE wave: all stage
    //      hand-offs intra-wave (HW in-order DS + CFENCE). No barriers inside.
    //      16 independent waves stagger LDS bursts against VALU bursts. ----
    {
        const int col = wave;
        const bool act = (t0 + col) < NFRAMES;
        C2* buf = fbuf[col];
        C2 v[8];

        // stage 1: [lane + 64c] -> [lane + 64m0]  (lane-local address set)
        if (act) {
            #pragma unroll
            for (int c = 0; c < 8; ++c) v[c] = buf[IDX(lane + 64*c)];
            idft8(v);
            #pragma unroll
            for (int m0 = 0; m0 < 8; ++m0) buf[IDX(lane + 64*m0)] = v[m0];
        }
        CFENCE();   // intra-wave RAW: stage-1 writes -> stage-2 reads (HW in-order DS)

        // stage 2: [a + 8b + 64m0] --tw--> [a + 8m1 + 64m0]  (lane-local address set)
        const int base2 = a2 + 64*m02;
        if (act) {
            #pragma unroll
            for (int bb = 0; bb < 8; ++bb) v[bb] = buf[IDX(base2 + 8*bb)];
            #pragma unroll
            for (int bb = 1; bb < 8; ++bb) v[bb] = cmul(v[bb], {c2r[bb], c2i[bb]});
            idft8(v);
            #pragma unroll
            for (int m1 = 0; m1 < 8; ++m1) buf[IDX(base2 + 8*m1)] = v[m1];
        }
        CFENCE();   // intra-wave RAW: stage-2 writes -> stage-3 reads

        // stage 3: contiguous read [8*lane + a], tw, idft8 (no writes yet)
        if (act) {
            #pragma unroll
            for (int aa = 0; aa < 8; ++aa) v[aa] = buf[IDX(8*lane + aa)];
            #pragma unroll
            for (int aa = 1; aa < 8; ++aa) v[aa] = cmul(v[aa], {c3r[aa], c3i[aa]});
            idft8(v);
        }
        // window coefficients (lane-dependent only)
        float2 wv[8];
        #pragma unroll
        for (int m2 = 0; m2 < 8; ++m2) wv[m2] = *(const float2*)&swin[2*(up + 64*m2)];
        CFENCE();   // intra-wave WAR: stage-3 reads precede linear overwrite (in-order DS)

        // unpack z[m] -> x[2m], x[2m+1]; apply window; write frame as floats (contiguous)
        if (act) {
            float* f = (float*)buf;
            #pragma unroll
            for (int m2 = 0; m2 < 8; ++m2) {
                int n = 2*(up + 64*m2);
                float2 val = { v[m2].x * wv[m2].x, v[m2].y * wv[m2].y };
                *(float2*)&f[n] = val;
            }
        }
    }
    __syncthreads();   // cross-wave: all columns final -> phase-3 reads any column

    // ---- phase 3: finalize exclusive span: sum <=4 windowed frames + env division ----
    // Fast path: p mod 256 is per-thread invariant -> envelope (4 taps + 1 rcp) hoisted.
    int p_start = (j == 0) ? 0 : (t0 + 3) * HOPS;
    int p_end   = (t0 + COLS) * HOPS;
    if (p_end > FULL_PER_B) p_end = FULL_PER_B;
    float* outb = out + (size_t)b * OUT_PER_B;
    const float* fb = (const float*)fbuf;    // row stride = 2*FSTRIDE = 1150 floats
    const int p0 = p_start + tid;
    const int q  = p0 & 255;                 // stride NTHREADS=1024 ≡ 0 mod 256 preserves q
    float w3 = swin[q], w2 = swin[q+256], w1 = swin[q+512], w0 = swin[q+768];
    float inv4 = 1.0f / fmaxf(w0*w0 + w1*w1 + w2*w2 + w3*w3, 1e-11f);
    for (int p = p0; p < p_end; p += NTHREADS) {
        if (p >= 768 && p < 524288) {
            // interior: exactly 4 frames, env per-thread invariant
            int d = ((p >> 8) - 3) - t0;         // 0..COLS-4
            const float* r = fb + (size_t)d * (2*FSTRIDE);
            float sum = r[q+768] + r[(2*FSTRIDE) + q+512] + r[(4*FSTRIDE) + q+256]
                      + r[(6*FSTRIDE) + q];
            outb[p - PADL] = sum * inv4;
        } else {
            int o = p - PADL;
            if (o < 0 || o >= OUT_PER_B) continue;
            int thi = p >> 8;          if (thi > NFRAMES-1) thi = NFRAMES-1;
            int tlo = (p - 768) >> 8;  if (tlo < 0) tlo = 0;
            float sum = 0.f, env = 0.f;
            for (int t = tlo; t <= thi; ++t) {
                int n = p - (t << 8);
                float w = swin[n];
                sum += fb[(size_t)(t - t0) * (2*FSTRIDE) + n];
                env += w * w;
            }
            outb[o] = sum / fmaxf(env, 1e-11f);
        }
    }
}

extern "C" void kernel_launch(void* const* d_in, const int* in_sizes, int n_in,
                              void* d_out, int out_size, void* d_ws, size_t ws_size,
                              hipStream_t stream) {
    const float* sr  = (const float*)d_in[0];
    const float* si  = (const float*)d_in[1];
    const float* win = (const float*)d_in[2];
    float* out = (float*)d_out;
    istft_kernel<<<dim3(BATCH*JBLK), dim3(NTHREADS), 0, stream>>>(sr, si, win, out);
}